// Round 4
// baseline (306.003 us; speedup 1.0000x reference)
//
#include <hip/hip_runtime.h>
#include <hip/hip_bf16.h>
#include <stdint.h>

// Problem constants
#define M_DIM 8192   // B*S = 4*2048
#define N_C   4096   // contraction dim (N in reference)
#define K_OUT 4096   // output features (K in reference)
#define NGRP  32
#define NT64  (N_C / 64)   // 64 K-tiles of 64

typedef __attribute__((ext_vector_type(8))) short bf16x8;
typedef __attribute__((ext_vector_type(4))) float f32x4;

// fp32 -> bf16, round-to-nearest-even (inputs are finite)
__device__ __forceinline__ unsigned short f2b(float f) {
  unsigned u = __float_as_uint(f);
  return (unsigned short)((u + 0x7fffu + ((u >> 16) & 1u)) >> 16);
}

__device__ __forceinline__ void gload_lds16(const void* g, void* l) {
  __builtin_amdgcn_global_load_lds(
      (const __attribute__((address_space(1))) void*)g,
      (__attribute__((address_space(3))) void*)l,
      16, 0, 0);
}

// ---- x fp32 -> bf16 ----
__global__ void convert_x_kernel(const float* __restrict__ x,
                                 unsigned short* __restrict__ xb) {
  const int total = (M_DIM * N_C) / 8;
  const int stride = gridDim.x * blockDim.x;
  for (int i = blockIdx.x * blockDim.x + threadIdx.x; i < total; i += stride) {
    const float4* p = (const float4*)(x + (size_t)i * 8);
    float4 a = p[0];
    float4 b = p[1];
    union { unsigned short u[8]; uint4 v; } o;
    o.u[0] = f2b(a.x); o.u[1] = f2b(a.y); o.u[2] = f2b(a.z); o.u[3] = f2b(a.w);
    o.u[4] = f2b(b.x); o.u[5] = f2b(b.y); o.u[6] = f2b(b.z); o.u[7] = f2b(b.w);
    *(uint4*)(xb + (size_t)i * 8) = o.v;
  }
}

// ---- W dequant -> bf16 [K_OUT][N_C] ----
__global__ void dequant_w_kernel(const int* __restrict__ Wq,
                                 const float* __restrict__ scales,
                                 const float* __restrict__ zeros,
                                 const float* __restrict__ mu1,
                                 const float* __restrict__ mu2,
                                 unsigned short* __restrict__ wb) {
  const int total = (K_OUT * N_C) / 8;
  const int stride = gridDim.x * blockDim.x;
  for (int i = blockIdx.x * blockDim.x + threadIdx.x; i < total; i += stride) {
    const int k  = i >> 9;
    const int nc = (i & 511) << 3;
    const int g  = nc >> 7;
    const float s = scales[k * NGRP + g];
    const float z = zeros[k * NGRP + g];
    const float f  = s * mu2[k];
    const float zf = z * f;
    const int4* q4 = (const int4*)(Wq + (size_t)k * N_C + nc);
    int4 q0 = q4[0], q1 = q4[1];
    const float4* m4 = (const float4*)(mu1 + nc);
    float4 m0 = m4[0], m1 = m4[1];
    union { unsigned short u[8]; uint4 v; } o;
    o.u[0] = f2b(((float)q0.x * f - zf) * m0.x);
    o.u[1] = f2b(((float)q0.y * f - zf) * m0.y);
    o.u[2] = f2b(((float)q0.z * f - zf) * m0.z);
    o.u[3] = f2b(((float)q0.w * f - zf) * m0.w);
    o.u[4] = f2b(((float)q1.x * f - zf) * m1.x);
    o.u[5] = f2b(((float)q1.y * f - zf) * m1.y);
    o.u[6] = f2b(((float)q1.z * f - zf) * m1.z);
    o.u[7] = f2b(((float)q1.w * f - zf) * m1.w);
    *(uint4*)(wb + (size_t)i * 8) = o.v;
  }
}

// ---- 8-phase bf16 GEMM (m201-style): out[m][n] = sum_k Xb[m][k]*Wb[n][k]+bias
// 256x256 tile, BK=64, 8 waves (2Mx4N), dbuf=2 x 64KB.
// Buffer layout (64 KB): [A-k0 16K][A-k1 16K][B-k0 16K][B-k1 16K]; each
// sub-block = 256 rows x 64 B, swizzled slot^=(row>>1)&3 (R2-verified, 0 conflicts).
// 4 phases per K-tile: (mh,kh) = (0,0),(1,0),(0,1),(1,1). Per phase:
// {4-or-8 ds_read_b128; 2 global_load_lds; [vmcnt(4)]; s_barrier; 16 MFMA; s_barrier}.
// Staging of tile t+1 during t, in 8 consumption-ordered 8KB units:
//  u1=A(0,0) u2=Bk0_L u3=Bk0_H u4=A(1,0) u5=A(0,1) u6=Bk1_L u7=Bk1_H u8=A(1,1)
// Ledger: vmcnt(4)@P4(t-1) proves u1..u4(t) (exactly P1+P2(t)'s reads);
//         vmcnt(4)@P2(t)   proves u5..u8(t) (exactly P3+P4(t)'s reads).
// In-flight never below 4 loads except the peeled final tile (vmcnt(0) once).
// Buffer safety: staging t+1 only, during t; all tile-(t) reads are data-dep
// drained before each wave's P4(t) MFMAs, and every wave passes P4(t)'s
// closing barrier before any wave stages into buf[t&1] at P1(t+1).
__global__ __launch_bounds__(512, 2) void gemm_bf16_kernel(
    const unsigned short* __restrict__ Xb,   // [M_DIM][N_C] bf16
    const unsigned short* __restrict__ Wb,   // [K_OUT][N_C] bf16
    const float* __restrict__ bias,          // [K_OUT]
    float* __restrict__ out) {               // [M_DIM][K_OUT]
  __shared__ unsigned short smem[65536];     // 128 KiB

  // XCD-aware bijective swizzle: 512 blocks, 8 XCDs, 64 per XCD
  const int bid = blockIdx.x;
  const int swz = (bid & 7) * 64 + (bid >> 3);
  const int n0 = (swz & 15) * 256;
  const int m0 = (swz >> 4) * 256;

  const int tid = threadIdx.x;
  const int w   = tid >> 6;
  const int l   = tid & 63;
  const int wr  = w >> 2;     // 0..1 -> 128 rows
  const int wc  = w & 3;      // 0..3 -> 64 cols

  const char* Xc = (const char*)Xb;
  const char* Wc = (const char*)Wb;
  char* ldsc = (char*)smem;

  // ---- staging constants (linear LDS dst, inverse-swizzled global src) ----
  const int rowA0 = (w >> 2) * 128 + (w & 3) * 16 + (l >> 2);  // {0-63}u{128-191}
  const int rowB0 = w * 16 + (l >> 2);                          // 0-127
  const int slotA = (l & 3) ^ ((rowA0 >> 1) & 3);
  const int slotB = (l & 3) ^ ((rowB0 >> 1) & 3);
  const char* srcA0 = Xc + (size_t)(m0 + rowA0) * 8192 + slotA * 16;
  const char* srcB0 = Wc + (size_t)(n0 + rowB0) * 8192 + slotB * 16;
  const int dstA0 = rowA0 * 64 + (l & 3) * 16;           // within A region
  const int dstB0 = 32768 + rowB0 * 64 + (l & 3) * 16;   // B region base

  // ---- swizzled ds_read byte offsets ----
  const int physk = (l >> 4) ^ (((l & 15) >> 1) & 3);
  const int offA = (wr * 128 + (l & 15)) * 64 + physk * 16;
  const int offB = 32768 + (wc * 64 + (l & 15)) * 64 + physk * 16;

  f32x4 acc[8][4] = {};
  bf16x8 bfv[4];

#define STG_P1(tt) { char* nb = ldsc + (((tt)+1)&1)*65536;                   \
    const size_t ko = (size_t)((tt)+1)*128;                                  \
    gload_lds16(srcA0 + ko, nb + dstA0);                                     \
    gload_lds16(srcB0 + ko, nb + dstB0); }
#define STG_P2(tt) { char* nb = ldsc + (((tt)+1)&1)*65536;                   \
    const size_t ko = (size_t)((tt)+1)*128;                                  \
    gload_lds16(srcB0 + 1048576 + ko, nb + dstB0 + 8192);                    \
    gload_lds16(srcA0 + 524288 + ko, nb + dstA0 + 4096); }
#define STG_P3(tt) { char* nb = ldsc + (((tt)+1)&1)*65536;                   \
    const size_t ko = (size_t)((tt)+1)*128 + 64;                             \
    gload_lds16(srcA0 + ko, nb + 16384 + dstA0);                             \
    gload_lds16(srcB0 + ko, nb + 16384 + dstB0); }
#define STG_P4(tt) { char* nb = ldsc + (((tt)+1)&1)*65536;                   \
    const size_t ko = (size_t)((tt)+1)*128 + 64;                             \
    gload_lds16(srcB0 + 1048576 + ko, nb + 16384 + dstB0 + 8192);            \
    gload_lds16(srcA0 + 524288 + ko, nb + 16384 + dstA0 + 4096); }

#define VM4 asm volatile("s_waitcnt vmcnt(4)" ::: "memory");
#define VM0 asm volatile("s_waitcnt vmcnt(0)" ::: "memory");
#define VMN ((void)0);

#define PHASE(mh, kh, LOADB, tt, STG, VM)                                    \
  { const int bufo = ((tt) & 1) * 65536;                                     \
    if (LOADB) { _Pragma("unroll") for (int j = 0; j < 4; ++j)               \
      bfv[j] = *(const bf16x8*)(ldsc + bufo + (kh)*16384 + offB + j*1024); } \
    bf16x8 af[4];                                                            \
    _Pragma("unroll") for (int i = 0; i < 4; ++i)                            \
      af[i] = *(const bf16x8*)(ldsc + bufo + (kh)*16384 + offA + (mh)*4096 + i*1024); \
    STG                                                                      \
    VM                                                                       \
    asm volatile("s_barrier" ::: "memory");                                  \
    __builtin_amdgcn_s_setprio(1);                                           \
    _Pragma("unroll") for (int j = 0; j < 4; ++j)                            \
      _Pragma("unroll") for (int i = 0; i < 4; ++i)                          \
        acc[(mh)*4+i][j] = __builtin_amdgcn_mfma_f32_16x16x32_bf16(          \
            af[i], bfv[j], acc[(mh)*4+i][j], 0, 0, 0);                       \
    __builtin_amdgcn_s_setprio(0);                                           \
    asm volatile("s_barrier" ::: "memory"); }

  // Prologue: stage tile 0's 8 units in ledger order; vmcnt(4) proves u1..u4.
  gload_lds16(srcA0,                 ldsc + dstA0);            // u1
  gload_lds16(srcB0,                 ldsc + dstB0);            // u2
  gload_lds16(srcB0 + 1048576,       ldsc + dstB0 + 8192);     // u3
  gload_lds16(srcA0 + 524288,        ldsc + dstA0 + 4096);     // u4
  gload_lds16(srcA0 + 64,            ldsc + 16384 + dstA0);            // u5
  gload_lds16(srcB0 + 64,            ldsc + 16384 + dstB0);            // u6
  gload_lds16(srcB0 + 1048576 + 64,  ldsc + 16384 + dstB0 + 8192);     // u7
  gload_lds16(srcA0 + 524288 + 64,   ldsc + 16384 + dstA0 + 4096);     // u8
  asm volatile("s_waitcnt vmcnt(4)\n\ts_barrier" ::: "memory");

#pragma unroll 1
  for (int kt = 0; kt < NT64 - 1; ++kt) {
    PHASE(0, 0, 1, kt, STG_P1(kt), VMN)
    PHASE(1, 0, 0, kt, STG_P2(kt), VM4)
    PHASE(0, 1, 1, kt, STG_P3(kt), VMN)
    PHASE(1, 1, 0, kt, STG_P4(kt), VM4)
  }
  // Peeled final tile: no staging; one vmcnt(0) to prove u5..u8(63).
  PHASE(0, 0, 1, NT64 - 1, VMN, VMN)
  PHASE(1, 0, 0, NT64 - 1, VMN, VM0)
  PHASE(0, 1, 1, NT64 - 1, VMN, VMN)
  PHASE(1, 1, 0, NT64 - 1, VMN, VMN)

#undef PHASE
#undef STG_P1
#undef STG_P2
#undef STG_P3
#undef STG_P4

  // Epilogue: C/D layout col=lane&15, row=(lane>>4)*4+reg (verified R1/R2).
  // acc index: idx = mh*4+i -> row base wr*128 + mh*64 + i*16.
#pragma unroll
  for (int j = 0; j < 4; ++j) {
    const int col = n0 + wc * 64 + j * 16 + (l & 15);
    const float bv = bias[col];
#pragma unroll
    for (int idx = 0; idx < 8; ++idx) {
      const int row = m0 + wr * 128 + (idx >> 2) * 64 + (idx & 3) * 16 + (l >> 4) * 4;
#pragma unroll
      for (int rr = 0; rr < 4; ++rr)
        out[(size_t)(row + rr) * K_OUT + col] = acc[idx][j][rr] + bv;
    }
  }
}

extern "C" void kernel_launch(void* const* d_in, const int* in_sizes, int n_in,
                              void* d_out, int out_size, void* d_ws, size_t ws_size,
                              hipStream_t stream) {
  const float* x      = (const float*)d_in[0];
  const int*   Wq     = (const int*)d_in[1];
  const float* scales = (const float*)d_in[2];
  const float* zeros  = (const float*)d_in[3];
  const float* mu1    = (const float*)d_in[4];
  const float* mu2    = (const float*)d_in[5];
  const float* bias   = (const float*)d_in[6];
  float* out = (float*)d_out;

  unsigned short* xb = (unsigned short*)d_ws;
  unsigned short* wb = xb + (size_t)M_DIM * N_C;

  convert_x_kernel<<<2048, 256, 0, stream>>>(x, xb);
  dequant_w_kernel<<<2048, 256, 0, stream>>>(Wq, scales, zeros, mu1, mu2, wb);

  dim3 grid((M_DIM / 256) * (K_OUT / 256));   // 512 blocks
  gemm_bf16_kernel<<<grid, 512, 0, stream>>>(xb, wb, bias, out);
}

// Round 5
// 303.564 us; speedup vs baseline: 1.0080x; 1.0080x over previous
//
#include <hip/hip_runtime.h>
#include <hip/hip_bf16.h>
#include <stdint.h>

// Problem constants
#define M_DIM 8192   // B*S = 4*2048
#define N_C   4096   // contraction dim (N in reference)
#define K_OUT 4096   // output features (K in reference)
#define NGRP  32
#define NT64  (N_C / 64)   // 64 K-tiles of 64

typedef __attribute__((ext_vector_type(8))) short bf16x8;
typedef __attribute__((ext_vector_type(4))) float f32x4;

// fp32 -> bf16, round-to-nearest-even (inputs are finite)
__device__ __forceinline__ unsigned short f2b(float f) {
  unsigned u = __float_as_uint(f);
  return (unsigned short)((u + 0x7fffu + ((u >> 16) & 1u)) >> 16);
}

__device__ __forceinline__ void gload_lds16(const void* g, void* l) {
  __builtin_amdgcn_global_load_lds(
      (const __attribute__((address_space(1))) void*)g,
      (__attribute__((address_space(3))) void*)l,
      16, 0, 0);
}

// ---- x fp32 -> bf16 ----
__global__ void convert_x_kernel(const float* __restrict__ x,
                                 unsigned short* __restrict__ xb) {
  const int total = (M_DIM * N_C) / 8;
  const int stride = gridDim.x * blockDim.x;
  for (int i = blockIdx.x * blockDim.x + threadIdx.x; i < total; i += stride) {
    const float4* p = (const float4*)(x + (size_t)i * 8);
    float4 a = p[0];
    float4 b = p[1];
    union { unsigned short u[8]; uint4 v; } o;
    o.u[0] = f2b(a.x); o.u[1] = f2b(a.y); o.u[2] = f2b(a.z); o.u[3] = f2b(a.w);
    o.u[4] = f2b(b.x); o.u[5] = f2b(b.y); o.u[6] = f2b(b.z); o.u[7] = f2b(b.w);
    *(uint4*)(xb + (size_t)i * 8) = o.v;
  }
}

// ---- W dequant -> bf16 [K_OUT][N_C] ----
__global__ void dequant_w_kernel(const int* __restrict__ Wq,
                                 const float* __restrict__ scales,
                                 const float* __restrict__ zeros,
                                 const float* __restrict__ mu1,
                                 const float* __restrict__ mu2,
                                 unsigned short* __restrict__ wb) {
  const int total = (K_OUT * N_C) / 8;
  const int stride = gridDim.x * blockDim.x;
  for (int i = blockIdx.x * blockDim.x + threadIdx.x; i < total; i += stride) {
    const int k  = i >> 9;
    const int nc = (i & 511) << 3;
    const int g  = nc >> 7;
    const float s = scales[k * NGRP + g];
    const float z = zeros[k * NGRP + g];
    const float f  = s * mu2[k];
    const float zf = z * f;
    const int4* q4 = (const int4*)(Wq + (size_t)k * N_C + nc);
    int4 q0 = q4[0], q1 = q4[1];
    const float4* m4 = (const float4*)(mu1 + nc);
    float4 m0 = m4[0], m1 = m4[1];
    union { unsigned short u[8]; uint4 v; } o;
    o.u[0] = f2b(((float)q0.x * f - zf) * m0.x);
    o.u[1] = f2b(((float)q0.y * f - zf) * m0.y);
    o.u[2] = f2b(((float)q0.z * f - zf) * m0.z);
    o.u[3] = f2b(((float)q0.w * f - zf) * m0.w);
    o.u[4] = f2b(((float)q1.x * f - zf) * m1.x);
    o.u[5] = f2b(((float)q1.y * f - zf) * m1.y);
    o.u[6] = f2b(((float)q1.z * f - zf) * m1.z);
    o.u[7] = f2b(((float)q1.w * f - zf) * m1.w);
    *(uint4*)(wb + (size_t)i * 8) = o.v;
  }
}

// ---- 8-phase bf16 GEMM: out[m][n] = sum_k Xb[m][k]*Wb[n][k]+bias[n]
// Geometry identical to R4 (256x256, BK=64, 8 waves 2Mx4N, dbuf=2x64KB,
// swizzle slot^=(row>>1)&3, staging ledger u1..u8, vmcnt(4) at P2/P4).
// R5 change (sync semantics ONLY): intrinsic s_barrier (no "memory"
// scheduling fence) per m201's template; "memory" clobber kept ONLY on the
// two per-K-tile vmcnt ledger fences (VM4@P2, VM4@P4) and final VM0.
// Ledger safety under scheduling freedom:
//  - P1(t) reads u1..u4(t): pinned after VM4@P4(t-1) fence which proves them.
//  - P3(t) reads u5..u8(t): pinned after VM4@P2(t) fence which proves them.
//  - staging targets buf[(t+1)&1] != read buffer buf[t&1]; runtime order of
//    barriers/waits/gload_lds preserved (side-effecting ops stay in order).
__global__ __launch_bounds__(512, 2) void gemm_bf16_kernel(
    const unsigned short* __restrict__ Xb,   // [M_DIM][N_C] bf16
    const unsigned short* __restrict__ Wb,   // [K_OUT][N_C] bf16
    const float* __restrict__ bias,          // [K_OUT]
    float* __restrict__ out) {               // [M_DIM][K_OUT]
  __shared__ unsigned short smem[65536];     // 128 KiB

  // XCD-aware bijective swizzle: 512 blocks, 8 XCDs, 64 per XCD
  const int bid = blockIdx.x;
  const int swz = (bid & 7) * 64 + (bid >> 3);
  const int n0 = (swz & 15) * 256;
  const int m0 = (swz >> 4) * 256;

  const int tid = threadIdx.x;
  const int w   = tid >> 6;
  const int l   = tid & 63;
  const int wr  = w >> 2;     // 0..1 -> 128 rows
  const int wc  = w & 3;      // 0..3 -> 64 cols

  const char* Xc = (const char*)Xb;
  const char* Wc = (const char*)Wb;
  char* ldsc = (char*)smem;

  // ---- staging constants (linear LDS dst, inverse-swizzled global src) ----
  const int rowA0 = (w >> 2) * 128 + (w & 3) * 16 + (l >> 2);  // {0-63}u{128-191}
  const int rowB0 = w * 16 + (l >> 2);                          // 0-127
  const int slotA = (l & 3) ^ ((rowA0 >> 1) & 3);
  const int slotB = (l & 3) ^ ((rowB0 >> 1) & 3);
  const char* srcA0 = Xc + (size_t)(m0 + rowA0) * 8192 + slotA * 16;
  const char* srcB0 = Wc + (size_t)(n0 + rowB0) * 8192 + slotB * 16;
  const int dstA0 = rowA0 * 64 + (l & 3) * 16;           // within A region
  const int dstB0 = 32768 + rowB0 * 64 + (l & 3) * 16;   // B region base

  // ---- swizzled ds_read byte offsets ----
  const int physk = (l >> 4) ^ (((l & 15) >> 1) & 3);
  const int offA = (wr * 128 + (l & 15)) * 64 + physk * 16;
  const int offB = 32768 + (wc * 64 + (l & 15)) * 64 + physk * 16;

  f32x4 acc[8][4] = {};
  bf16x8 bfv[4];

#define STG_P1(tt) { char* nb = ldsc + (((tt)+1)&1)*65536;                   \
    const size_t ko = (size_t)((tt)+1)*128;                                  \
    gload_lds16(srcA0 + ko, nb + dstA0);                                     \
    gload_lds16(srcB0 + ko, nb + dstB0); }
#define STG_P2(tt) { char* nb = ldsc + (((tt)+1)&1)*65536;                   \
    const size_t ko = (size_t)((tt)+1)*128;                                  \
    gload_lds16(srcB0 + 1048576 + ko, nb + dstB0 + 8192);                    \
    gload_lds16(srcA0 + 524288 + ko, nb + dstA0 + 4096); }
#define STG_P3(tt) { char* nb = ldsc + (((tt)+1)&1)*65536;                   \
    const size_t ko = (size_t)((tt)+1)*128 + 64;                             \
    gload_lds16(srcA0 + ko, nb + 16384 + dstA0);                             \
    gload_lds16(srcB0 + ko, nb + 16384 + dstB0); }
#define STG_P4(tt) { char* nb = ldsc + (((tt)+1)&1)*65536;                   \
    const size_t ko = (size_t)((tt)+1)*128 + 64;                             \
    gload_lds16(srcB0 + 1048576 + ko, nb + 16384 + dstB0 + 8192);            \
    gload_lds16(srcA0 + 524288 + ko, nb + 16384 + dstA0 + 4096); }

#define VM4 asm volatile("s_waitcnt vmcnt(4)" ::: "memory");
#define VM0 asm volatile("s_waitcnt vmcnt(0)" ::: "memory");
#define VMN ((void)0);

#define PHASE(mh, kh, LOADB, tt, STG, VM)                                    \
  { const int bufo = ((tt) & 1) * 65536;                                     \
    if (LOADB) { _Pragma("unroll") for (int j = 0; j < 4; ++j)               \
      bfv[j] = *(const bf16x8*)(ldsc + bufo + (kh)*16384 + offB + j*1024); } \
    bf16x8 af[4];                                                            \
    _Pragma("unroll") for (int i = 0; i < 4; ++i)                            \
      af[i] = *(const bf16x8*)(ldsc + bufo + (kh)*16384 + offA + (mh)*4096 + i*1024); \
    STG                                                                      \
    VM                                                                       \
    __builtin_amdgcn_s_barrier();                                            \
    __builtin_amdgcn_s_setprio(1);                                           \
    _Pragma("unroll") for (int j = 0; j < 4; ++j)                            \
      _Pragma("unroll") for (int i = 0; i < 4; ++i)                          \
        acc[(mh)*4+i][j] = __builtin_amdgcn_mfma_f32_16x16x32_bf16(          \
            af[i], bfv[j], acc[(mh)*4+i][j], 0, 0, 0);                       \
    __builtin_amdgcn_s_setprio(0);                                           \
    __builtin_amdgcn_s_barrier(); }

  // Prologue: stage tile 0's 8 units in ledger order; vmcnt(4) proves u1..u4.
  gload_lds16(srcA0,                 ldsc + dstA0);            // u1
  gload_lds16(srcB0,                 ldsc + dstB0);            // u2
  gload_lds16(srcB0 + 1048576,       ldsc + dstB0 + 8192);     // u3
  gload_lds16(srcA0 + 524288,        ldsc + dstA0 + 4096);     // u4
  gload_lds16(srcA0 + 64,            ldsc + 16384 + dstA0);            // u5
  gload_lds16(srcB0 + 64,            ldsc + 16384 + dstB0);            // u6
  gload_lds16(srcB0 + 1048576 + 64,  ldsc + 16384 + dstB0 + 8192);     // u7
  gload_lds16(srcA0 + 524288 + 64,   ldsc + 16384 + dstA0 + 4096);     // u8
  VM4
  __builtin_amdgcn_s_barrier();

#pragma unroll 1
  for (int kt = 0; kt < NT64 - 1; ++kt) {
    PHASE(0, 0, 1, kt, STG_P1(kt), VMN)
    PHASE(1, 0, 0, kt, STG_P2(kt), VM4)
    PHASE(0, 1, 1, kt, STG_P3(kt), VMN)
    PHASE(1, 1, 0, kt, STG_P4(kt), VM4)
  }
  // Peeled final tile: no staging; one vmcnt(0) to prove u5..u8(63).
  PHASE(0, 0, 1, NT64 - 1, VMN, VMN)
  PHASE(1, 0, 0, NT64 - 1, VMN, VM0)
  PHASE(0, 1, 1, NT64 - 1, VMN, VMN)
  PHASE(1, 1, 0, NT64 - 1, VMN, VMN)

#undef PHASE
#undef STG_P1
#undef STG_P2
#undef STG_P3
#undef STG_P4

  // Epilogue: C/D layout col=lane&15, row=(lane>>4)*4+reg (verified R1/R2).
#pragma unroll
  for (int j = 0; j < 4; ++j) {
    const int col = n0 + wc * 64 + j * 16 + (l & 15);
    const float bv = bias[col];
#pragma unroll
    for (int idx = 0; idx < 8; ++idx) {
      const int row = m0 + wr * 128 + (idx >> 2) * 64 + (idx & 3) * 16 + (l >> 4) * 4;
#pragma unroll
      for (int rr = 0; rr < 4; ++rr)
        out[(size_t)(row + rr) * K_OUT + col] = acc[idx][j][rr] + bv;
    }
  }
}

extern "C" void kernel_launch(void* const* d_in, const int* in_sizes, int n_in,
                              void* d_out, int out_size, void* d_ws, size_t ws_size,
                              hipStream_t stream) {
  const float* x      = (const float*)d_in[0];
  const int*   Wq     = (const int*)d_in[1];
  const float* scales = (const float*)d_in[2];
  const float* zeros  = (const float*)d_in[3];
  const float* mu1    = (const float*)d_in[4];
  const float* mu2    = (const float*)d_in[5];
  const float* bias   = (const float*)d_in[6];
  float* out = (float*)d_out;

  unsigned short* xb = (unsigned short*)d_ws;
  unsigned short* wb = xb + (size_t)M_DIM * N_C;

  convert_x_kernel<<<2048, 256, 0, stream>>>(x, xb);
  dequant_w_kernel<<<2048, 256, 0, stream>>>(Wq, scales, zeros, mu1, mu2, wb);

  dim3 grid((M_DIM / 256) * (K_OUT / 256));   // 512 blocks
  gemm_bf16_kernel<<<grid, 512, 0, stream>>>(xb, wb, bias, out);
}

// Round 6
// 302.716 us; speedup vs baseline: 1.0109x; 1.0028x over previous
//
#include <hip/hip_runtime.h>
#include <hip/hip_bf16.h>
#include <stdint.h>

// Problem constants
#define M_DIM 8192   // B*S = 4*2048
#define N_C   4096   // contraction dim (N in reference)
#define K_OUT 4096   // output features (K in reference)
#define NGRP  32
#define NT    (N_C / 32)   // 128 K-tiles of 32

typedef __attribute__((ext_vector_type(8))) short bf16x8;
typedef __attribute__((ext_vector_type(4))) float f32x4;

// fp32 -> bf16, round-to-nearest-even (inputs are finite)
__device__ __forceinline__ unsigned short f2b(float f) {
  unsigned u = __float_as_uint(f);
  return (unsigned short)((u + 0x7fffu + ((u >> 16) & 1u)) >> 16);
}

__device__ __forceinline__ void gload_lds16(const void* g, void* l) {
  __builtin_amdgcn_global_load_lds(
      (const __attribute__((address_space(1))) void*)g,
      (__attribute__((address_space(3))) void*)l,
      16, 0, 0);
}

// ---- x fp32 -> bf16 ----
__global__ void convert_x_kernel(const float* __restrict__ x,
                                 unsigned short* __restrict__ xb) {
  const int total = (M_DIM * N_C) / 8;
  const int stride = gridDim.x * blockDim.x;
  for (int i = blockIdx.x * blockDim.x + threadIdx.x; i < total; i += stride) {
    const float4* p = (const float4*)(x + (size_t)i * 8);
    float4 a = p[0];
    float4 b = p[1];
    union { unsigned short u[8]; uint4 v; } o;
    o.u[0] = f2b(a.x); o.u[1] = f2b(a.y); o.u[2] = f2b(a.z); o.u[3] = f2b(a.w);
    o.u[4] = f2b(b.x); o.u[5] = f2b(b.y); o.u[6] = f2b(b.z); o.u[7] = f2b(b.w);
    *(uint4*)(xb + (size_t)i * 8) = o.v;
  }
}

// ---- W dequant -> bf16 [K_OUT][N_C] ----
__global__ void dequant_w_kernel(const int* __restrict__ Wq,
                                 const float* __restrict__ scales,
                                 const float* __restrict__ zeros,
                                 const float* __restrict__ mu1,
                                 const float* __restrict__ mu2,
                                 unsigned short* __restrict__ wb) {
  const int total = (K_OUT * N_C) / 8;
  const int stride = gridDim.x * blockDim.x;
  for (int i = blockIdx.x * blockDim.x + threadIdx.x; i < total; i += stride) {
    const int k  = i >> 9;
    const int nc = (i & 511) << 3;
    const int g  = nc >> 7;
    const float s = scales[k * NGRP + g];
    const float z = zeros[k * NGRP + g];
    const float f  = s * mu2[k];
    const float zf = z * f;
    const int4* q4 = (const int4*)(Wq + (size_t)k * N_C + nc);
    int4 q0 = q4[0], q1 = q4[1];
    const float4* m4 = (const float4*)(mu1 + nc);
    float4 m0 = m4[0], m1 = m4[1];
    union { unsigned short u[8]; uint4 v; } o;
    o.u[0] = f2b(((float)q0.x * f - zf) * m0.x);
    o.u[1] = f2b(((float)q0.y * f - zf) * m0.y);
    o.u[2] = f2b(((float)q0.z * f - zf) * m0.z);
    o.u[3] = f2b(((float)q0.w * f - zf) * m0.w);
    o.u[4] = f2b(((float)q1.x * f - zf) * m1.x);
    o.u[5] = f2b(((float)q1.y * f - zf) * m1.y);
    o.u[6] = f2b(((float)q1.z * f - zf) * m1.z);
    o.u[7] = f2b(((float)q1.w * f - zf) * m1.w);
    *(uint4*)(wb + (size_t)i * 8) = o.v;
  }
}

// ---- Deep-pipelined bf16 GEMM (R3 structure + T19 SGB interleave) ----
// 256x256 tile, BK=32, 8 waves (2Mx4N, per-wave 128x64), 4 LDS buffers
// (128 KB), prefetch depth 3, counted vmcnt(8), one barrier per K-tile,
// XOR-swizzled LDS (0 conflicts, verified R2).
// R6 change: sched_group_barrier pins DS_READ/MFMA interleave so MFMA quads
// start after ~7 reads (counted lgkmcnt) instead of after all 12 -> DS
// service overlaps MFMA stream. Sync structure byte-identical to R3.
__global__ __launch_bounds__(512) void gemm_bf16_kernel(
    const unsigned short* __restrict__ Xb,   // [M_DIM][N_C] bf16
    const unsigned short* __restrict__ Wb,   // [K_OUT][N_C] bf16
    const float* __restrict__ bias,          // [K_OUT]
    float* __restrict__ out) {               // [M_DIM][K_OUT]
  __shared__ unsigned short smem[65536];     // 128 KiB: 4 bufs x 32 KiB

  // XCD-aware bijective swizzle: 512 blocks, 8 XCDs, 64 per XCD
  const int bid = blockIdx.x;
  const int swz = (bid & 7) * 64 + (bid >> 3);
  const int n0 = (swz & 15) * 256;
  const int m0 = (swz >> 4) * 256;

  const int tid = threadIdx.x;
  const int w   = tid >> 6;
  const int l   = tid & 63;
  const int wr  = w >> 2;     // 0..1 -> 128 rows each
  const int wc  = w & 3;      // 0..3 -> 64 cols each

  const char* Xc = (const char*)Xb;
  const char* Wc = (const char*)Wb;
  const char* srcA[2];
  const char* srcB[2];
  int dstOff[2];
#pragma unroll
  for (int e = 0; e < 2; ++e) {
    const int P  = (e * 8 + w) * 1024 + l * 16;
    const int r  = P >> 6;
    const int sl = ((P >> 4) & 3) ^ ((r >> 1) & 3);
    srcA[e] = Xc + (size_t)(m0 + r) * (N_C * 2) + sl * 16;
    srcB[e] = Wc + (size_t)(n0 + r) * (N_C * 2) + sl * 16;
    dstOff[e] = (e * 8 + w) * 1024;   // wave-uniform LDS byte offset
  }

  // ---- swizzled ds_read offsets (ushort units, within one 32KB buffer) ----
  int offa[8], offb[4];
#pragma unroll
  for (int i = 0; i < 8; ++i) {
    const int r  = wr * 128 + i * 16 + (l & 15);
    const int sl = (l >> 4) ^ ((r >> 1) & 3);
    offa[i] = (r * 64 + sl * 16) >> 1;
  }
#pragma unroll
  for (int j = 0; j < 4; ++j) {
    const int r  = wc * 64 + j * 16 + (l & 15);
    const int sl = (l >> 4) ^ ((r >> 1) & 3);
    offb[j] = (16384 + r * 64 + sl * 16) >> 1;
  }

  f32x4 acc[8][4] = {};
  char* ldsc = (char*)smem;

#define STAGE(tt)                                                            \
  { const int sb = ((tt) & 3) * 32768; const size_t ko = (size_t)(tt) * 64;  \
    gload_lds16(srcA[0] + ko, ldsc + sb + dstOff[0]);                        \
    gload_lds16(srcA[1] + ko, ldsc + sb + dstOff[1]);                        \
    gload_lds16(srcB[0] + ko, ldsc + sb + 16384 + dstOff[0]);                \
    gload_lds16(srcB[1] + ko, ldsc + sb + 16384 + dstOff[1]); }

  STAGE(0)
  STAGE(1)
  STAGE(2)

// SGB masks: DS_READ=0x100, MFMA=0x8, VMEM=0x10
#define SGB __builtin_amdgcn_sched_group_barrier
#define KSTEP(VMSTR, tt, DOSTAGE)                                            \
  { asm volatile("s_waitcnt vmcnt(" VMSTR ")\n\ts_barrier" ::: "memory");    \
    const unsigned short* bp = smem + ((tt) & 3) * 16384;                    \
    bf16x8 af[8]; bf16x8 bfv[4];                                             \
    bfv[0] = *(const bf16x8*)(bp + offb[0]);                                 \
    bfv[1] = *(const bf16x8*)(bp + offb[1]);                                 \
    bfv[2] = *(const bf16x8*)(bp + offb[2]);                                 \
    bfv[3] = *(const bf16x8*)(bp + offb[3]);                                 \
    _Pragma("unroll") for (int i = 0; i < 8; ++i)                            \
      af[i] = *(const bf16x8*)(bp + offa[i]);                                \
    if (DOSTAGE) STAGE((tt) + 3)                                             \
    _Pragma("unroll") for (int i = 0; i < 8; ++i)                            \
      _Pragma("unroll") for (int j = 0; j < 4; ++j)                          \
        acc[i][j] = __builtin_amdgcn_mfma_f32_16x16x32_bf16(af[i], bfv[j],   \
                                                            acc[i][j], 0, 0, 0); \
    /* pin: DS7 M4 (DS1 M4)x3 VMEM4 (DS1 M4)x2 M4 M4 -> >=2-group lookahead */ \
    SGB(0x100, 7, 0); SGB(0x8, 4, 0);                                        \
    SGB(0x100, 1, 0); SGB(0x8, 4, 0);                                        \
    SGB(0x100, 1, 0); SGB(0x8, 4, 0);                                        \
    SGB(0x100, 1, 0); SGB(0x8, 4, 0);                                        \
    SGB(0x10, 4, 0);                                                         \
    SGB(0x100, 1, 0); SGB(0x8, 4, 0);                                        \
    SGB(0x100, 1, 0); SGB(0x8, 4, 0);                                        \
    SGB(0x8, 4, 0); SGB(0x8, 4, 0); }

#pragma unroll 1
  for (int kt = 0; kt < NT - 3; ++kt) KSTEP("8", kt, 1)
  KSTEP("8", NT - 3, 0)
  KSTEP("4", NT - 2, 0)
  KSTEP("0", NT - 1, 0)

#undef KSTEP
#undef SGB
#undef STAGE

  // Epilogue: C/D layout col=lane&15, row=(lane>>4)*4+reg (verified R1)
#pragma unroll
  for (int j = 0; j < 4; ++j) {
    const int col = n0 + wc * 64 + j * 16 + (l & 15);
    const float bv = bias[col];
#pragma unroll
    for (int i = 0; i < 8; ++i) {
      const int row = m0 + wr * 128 + i * 16 + (l >> 4) * 4;
#pragma unroll
      for (int rr = 0; rr < 4; ++rr)
        out[(size_t)(row + rr) * K_OUT + col] = acc[i][j][rr] + bv;
    }
  }
}

extern "C" void kernel_launch(void* const* d_in, const int* in_sizes, int n_in,
                              void* d_out, int out_size, void* d_ws, size_t ws_size,
                              hipStream_t stream) {
  const float* x      = (const float*)d_in[0];
  const int*   Wq     = (const int*)d_in[1];
  const float* scales = (const float*)d_in[2];
  const float* zeros  = (const float*)d_in[3];
  const float* mu1    = (const float*)d_in[4];
  const float* mu2    = (const float*)d_in[5];
  const float* bias   = (const float*)d_in[6];
  float* out = (float*)d_out;

  unsigned short* xb = (unsigned short*)d_ws;
  unsigned short* wb = xb + (size_t)M_DIM * N_C;

  convert_x_kernel<<<2048, 256, 0, stream>>>(x, xb);
  dequant_w_kernel<<<2048, 256, 0, stream>>>(Wq, scales, zeros, mu1, mu2, wb);

  dim3 grid((M_DIM / 256) * (K_OUT / 256));   // 512 blocks
  gemm_bf16_kernel<<<grid, 512, 0, stream>>>(xb, wb, bias, out);
}